// Round 7
// baseline (107561.572 us; speedup 1.0000x reference)
//
#include <hip/hip_runtime.h>
#include <stdint.h>

#define SEQ   512
#define BATCH 64
#define INP   64
#define HID   1024
#define NBLK  256     // 128 layer-0 + 128 layer-1 blocks (wavefront pipeline)
#define NTHR  512     // 8 units (= 8 waves) x 64 batch; 128 blocks x 8 units = 1024 = HID
#define NU    8
#define CHK   32      // k-values per staged chunk
#define KG    8       // float4-groups per chunk (CHK/4)
#define NCH   32      // chunks per h vector (HID/CHK)
#define CHW   2048    // floats per chunk (CHK*64)
#define HBUF  65536   // floats per h slot (256 kg * 64 b * 4)

typedef float f4 __attribute__((ext_vector_type(4)));

// ---- coherent 16B load: bypasses L1 (sc0) + non-coherent per-XCD L2 (sc1) ----
__device__ __forceinline__ void cload4(f4* dst, const float* p) {
    asm volatile("global_load_dwordx4 %0, %1, off sc0 sc1"
                 : "=&v"(*dst) : "v"(p) : "memory");
}
#define WAITVM(n) do { asm volatile("s_waitcnt vmcnt(" #n ")" ::: "memory"); \
                       __builtin_amdgcn_sched_barrier(0); } while (0)
// raw chunk barrier: lgkm drain (ds_write visibility) + s_barrier, NO vmcnt drain
// (this is the r6 fix: __syncthreads emits vmcnt(0) and kills the prefetch)
#define BARR  do { __builtin_amdgcn_sched_barrier(0); \
                   asm volatile("s_waitcnt lgkmcnt(0)" ::: "memory"); \
                   __builtin_amdgcn_sched_barrier(0); \
                   __builtin_amdgcn_s_barrier(); \
                   __builtin_amdgcn_sched_barrier(0); } while (0)

__device__ __forceinline__ float cload(float* p) {
    return __hip_atomic_load(p, __ATOMIC_RELAXED, __HIP_MEMORY_SCOPE_AGENT);
}
__device__ __forceinline__ void cstore(float* p, float v) {
    __hip_atomic_store(p, v, __ATOMIC_RELAXED, __HIP_MEMORY_SCOPE_AGENT);
}
__device__ __forceinline__ float sigf(float x) { return 1.0f / (1.0f + __expf(-x)); }

// ---- one-time flag barrier (poison-safe window check, proven r2/r4) ----
__device__ __forceinline__ void flagbar(uint32_t* flags, int tid) {
    __syncthreads();
    if (tid == 0)
        __hip_atomic_store(&flags[blockIdx.x], 1u, __ATOMIC_RELAXED, __HIP_MEMORY_SCOPE_AGENT);
    if (tid < 64) {
        for (;;) {
            bool ok = true;
            #pragma unroll
            for (int i = 0; i < NBLK / 64; ++i) {
                uint32_t v = __hip_atomic_load(&flags[tid + i * 64], __ATOMIC_RELAXED,
                                               __HIP_MEMORY_SCOPE_AGENT);
                ok &= ((uint32_t)(v - 1u) < 0x10000000u);
            }
            if (__all(ok)) break;
        }
    }
    __syncthreads();
}

// ---- per-round counter barrier (proven r4): 8 monotonic group counters ----
// NBLK=256 -> 32 arrivals per group per round; target for round q is q*32.
__device__ __forceinline__ void bar_arrive(uint32_t* grp, int tid) {
    __syncthreads();   // drains this block's h/out stores (vmcnt(0) before s_barrier)
    if (tid == 0)
        __hip_atomic_fetch_add(&grp[blockIdx.x & 7], 1u, __ATOMIC_RELAXED,
                               __HIP_MEMORY_SCOPE_AGENT);
}
__device__ __forceinline__ void bar_wait(uint32_t* grp, uint32_t target, int tid) {
    if (tid < 64) {
        for (;;) {
            uint32_t v = __hip_atomic_load(&grp[tid & 7], __ATOMIC_RELAXED,
                                           __HIP_MEMORY_SCOPE_AGENT);
            if (__all((uint32_t)(v - target) < 0x10000000u)) break;
        }
    }
    __syncthreads();
}

// h buffers live in ws as fp32 [slot][kg][b][4]  (kg = k>>2): 16B per (kg,b).

// ============ fused wavefront kernel ============
// blocks 0..127  : layer 0, wave u owns unit ub+u; compute step t at round t
// blocks 128..255: layer 1, same mapping;          compute step t at round t+1
// Weights are read via wave-uniform pointers (s_load path, SMEM/lgkmcnt — no LDS,
// no vmcnt). h staged through LDS in 8KB chunks with a 2-deep asm-load pipeline
// that survives the raw per-chunk barriers (counted vmcnt, T3/T4).
__global__ void __launch_bounds__(NTHR, 2) lstm_fused(
    const float* __restrict__ x,
    const float* __restrict__ Wih0, const float* __restrict__ Whh0,
    const float* __restrict__ bih0, const float* __restrict__ bhh0,
    const float* __restrict__ Wih1, const float* __restrict__ Whh1,
    const float* __restrict__ bih1, const float* __restrict__ bhh1,
    float* __restrict__ out, float* __restrict__ h1buf, float* __restrict__ h2buf,
    uint32_t* __restrict__ flags, uint32_t* __restrict__ grp)
{
    __shared__ f4 st1[2][NTHR];   // 16 KB: h1-chunk double buffer
    __shared__ f4 st2[2][NTHR];   // 16 KB: h2-chunk double buffer (L1 only)
    const int tid = threadIdx.x;
    const int bk  = blockIdx.x;
    const bool Lb = (bk >= NBLK / 2);
    const int ub  = (Lb ? bk - NBLK / 2 : bk) * NU;
    const int b   = tid & 63;
    const int js  = ub + __builtin_amdgcn_readfirstlane(tid >> 6);  // wave-uniform unit

    const float* bi = Lb ? bih1 : bih0;
    const float* bh = Lb ? bhh1 : bhh0;
    const float bias0 = bi[0 * HID + js] + bh[0 * HID + js];
    const float bias1 = bi[1 * HID + js] + bh[1 * HID + js];
    const float bias2 = bi[2 * HID + js] + bh[2 * HID + js];
    const float bias3 = bi[3 * HID + js] + bh[3 * HID + js];

    // h(-1) = 0 in slot 0 (ws poisoned); each block zeroes its own units' entries
    cstore((Lb ? h2buf : h1buf) + (js >> 2) * 256 + b * 4 + (js & 3), 0.0f);
    if (bk < 8 && tid == 0) {
        __hip_atomic_store(&grp[bk], 0u, __ATOMIC_RELAXED, __HIP_MEMORY_SCOPE_AGENT);
        __threadfence();   // order ctr-zero before this block's flag post
    }
    float c = 0.0f;
    flagbar(flags, tid);

    if (!Lb) {
        // ---- layer 0: compute step t, arrive, xpart(t+1), wait ----
        const float4* wi0 = (const float4*)(Wih0 + (size_t)(0 * HID + js) * INP);
        const float4* wi1 = (const float4*)(Wih0 + (size_t)(1 * HID + js) * INP);
        const float4* wi2 = (const float4*)(Wih0 + (size_t)(2 * HID + js) * INP);
        const float4* wi3 = (const float4*)(Wih0 + (size_t)(3 * HID + js) * INP);
        const float4* wh0 = (const float4*)(Whh0 + (size_t)(0 * HID + js) * HID);
        const float4* wh1 = (const float4*)(Whh0 + (size_t)(1 * HID + js) * HID);
        const float4* wh2 = (const float4*)(Whh0 + (size_t)(2 * HID + js) * HID);
        const float4* wh3 = (const float4*)(Whh0 + (size_t)(3 * HID + js) * HID);
        float a0 = bias0, a1 = bias1, a2 = bias2, a3 = bias3;
        {   // xpart(0)
            const float4* xr = (const float4*)(x + (size_t)b * INP);
            #pragma unroll
            for (int k4 = 0; k4 < INP / 4; ++k4) {
                float4 xv = xr[k4];
                float4 u0 = wi0[k4], u1 = wi1[k4], u2 = wi2[k4], u3 = wi3[k4];
                a0 += u0.x * xv.x + u0.y * xv.y + u0.z * xv.z + u0.w * xv.w;
                a1 += u1.x * xv.x + u1.y * xv.y + u1.z * xv.z + u1.w * xv.w;
                a2 += u2.x * xv.x + u2.y * xv.y + u2.z * xv.z + u2.w * xv.w;
                a3 += u3.x * xv.x + u3.y * xv.y + u3.z * xv.z + u3.w * xv.w;
            }
        }
        #define CONSUME0(PAR, CB) do {                                          \
            _Pragma("unroll")                                                   \
            for (int kl = 0; kl < KG; ++kl) {                                   \
                f4 hv = st1[PAR][kl * 64 + b];                                  \
                int kg = (CB) + kl;                                             \
                float4 w0 = wh0[kg], w1 = wh1[kg], w2 = wh2[kg], w3 = wh3[kg];  \
                a0 += w0.x*hv.x + w0.y*hv.y + w0.z*hv.z + w0.w*hv.w;            \
                a1 += w1.x*hv.x + w1.y*hv.y + w1.z*hv.z + w1.w*hv.w;            \
                a2 += w2.x*hv.x + w2.y*hv.y + w2.z*hv.z + w2.w*hv.w;            \
                a3 += w3.x*hv.x + w3.y*hv.y + w3.z*hv.z + w3.w*hv.w;            \
            } } while (0)
        for (int t = 0; t < SEQ; ++t) {
            float* hr = h1buf + (t & 1) * HBUF;
            float* hw = h1buf + ((t & 1) ^ 1) * HBUF;
            f4 bA, bB;
            cload4(&bA, hr + tid * 4);
            cload4(&bB, hr + CHW + tid * 4);
            WAITVM(1);                       // chunk 0 arrived (chunk 1 in flight)
            st1[0][tid] = bA;
            cload4(&bA, hr + 2 * CHW + tid * 4);
            BARR;
            #pragma unroll 1
            for (int cc = 0; cc < NCH; cc += 2) {
                // even chunk cc: consume st1[0]; bank bB = chunk cc+1
                if (cc + 2 < NCH) { WAITVM(1); } else { WAITVM(0); }
                st1[1][tid] = bB;
                if (cc + 3 < NCH) cload4(&bB, hr + (size_t)(cc + 3) * CHW + tid * 4);
                CONSUME0(0, cc * KG);
                BARR;
                // odd chunk cc+1: consume st1[1]; bank bA = chunk cc+2
                if (cc + 2 < NCH) {
                    if (cc + 3 < NCH) { WAITVM(1); } else { WAITVM(0); }
                    st1[0][tid] = bA;
                    if (cc + 4 < NCH) cload4(&bA, hr + (size_t)(cc + 4) * CHW + tid * 4);
                }
                CONSUME0(1, (cc + 1) * KG);
                BARR;
            }
            float ig = sigf(a0), fg = sigf(a1), gg = tanhf(a2), og = sigf(a3);
            c = fg * c + ig * gg;
            float h = og * tanhf(c);
            cstore(hw + (js >> 2) * 256 + b * 4 + (js & 3), h);   // h1_t
            bar_arrive(grp, tid);
            if (t + 1 < SEQ) {
                a0 = bias0; a1 = bias1; a2 = bias2; a3 = bias3;
                const float4* xr = (const float4*)(x + ((size_t)(t + 1) * BATCH + b) * INP);
                #pragma unroll
                for (int k4 = 0; k4 < INP / 4; ++k4) {
                    float4 xv = xr[k4];
                    float4 u0 = wi0[k4], u1 = wi1[k4], u2 = wi2[k4], u3 = wi3[k4];
                    a0 += u0.x * xv.x + u0.y * xv.y + u0.z * xv.z + u0.w * xv.w;
                    a1 += u1.x * xv.x + u1.y * xv.y + u1.z * xv.z + u1.w * xv.w;
                    a2 += u2.x * xv.x + u2.y * xv.y + u2.z * xv.z + u2.w * xv.w;
                    a3 += u3.x * xv.x + u3.y * xv.y + u3.z * xv.z + u3.w * xv.w;
                }
                bar_wait(grp, (uint32_t)(t + 1) * 32u, tid);
            }
        }
    } else {
        // ---- layer 1: arrive, wait, compute step t ----
        const float4* vi0 = (const float4*)(Wih1 + (size_t)(0 * HID + js) * HID);
        const float4* vi1 = (const float4*)(Wih1 + (size_t)(1 * HID + js) * HID);
        const float4* vi2 = (const float4*)(Wih1 + (size_t)(2 * HID + js) * HID);
        const float4* vi3 = (const float4*)(Wih1 + (size_t)(3 * HID + js) * HID);
        const float4* vh0 = (const float4*)(Whh1 + (size_t)(0 * HID + js) * HID);
        const float4* vh1 = (const float4*)(Whh1 + (size_t)(1 * HID + js) * HID);
        const float4* vh2 = (const float4*)(Whh1 + (size_t)(2 * HID + js) * HID);
        const float4* vh3 = (const float4*)(Whh1 + (size_t)(3 * HID + js) * HID);
        #define CONSUME1(PAR, CB) do {                                          \
            _Pragma("unroll")                                                   \
            for (int kl = 0; kl < KG; ++kl) {                                   \
                f4 xv = st1[PAR][kl * 64 + b];                                  \
                f4 hv = st2[PAR][kl * 64 + b];                                  \
                int kg = (CB) + kl;                                             \
                float4 i0 = vi0[kg], i1 = vi1[kg], i2 = vi2[kg], i3 = vi3[kg];  \
                float4 h0 = vh0[kg], h1 = vh1[kg], h2 = vh2[kg], h3 = vh3[kg];  \
                a0 += i0.x*xv.x + i0.y*xv.y + i0.z*xv.z + i0.w*xv.w             \
                    + h0.x*hv.x + h0.y*hv.y + h0.z*hv.z + h0.w*hv.w;            \
                a1 += i1.x*xv.x + i1.y*xv.y + i1.z*xv.z + i1.w*xv.w             \
                    + h1.x*hv.x + h1.y*hv.y + h1.z*hv.z + h1.w*hv.w;            \
                a2 += i2.x*xv.x + i2.y*xv.y + i2.z*xv.z + i2.w*xv.w             \
                    + h2.x*hv.x + h2.y*hv.y + h2.z*hv.z + h2.w*hv.w;            \
                a3 += i3.x*xv.x + i3.y*xv.y + i3.z*xv.z + i3.w*xv.w             \
                    + h3.x*hv.x + h3.y*hv.y + h3.z*hv.z + h3.w*hv.w;            \
            } } while (0)
        for (int t = 0; t < SEQ; ++t) {
            bar_arrive(grp, tid);                          // h2[t-1] stores drained
            bar_wait(grp, (uint32_t)(t + 1) * 32u, tid);   // h1_t visible
            float* h1r = h1buf + ((t & 1) ^ 1) * HBUF;     // h1_t (L0 wrote this round)
            float* h2r = h2buf + (t & 1) * HBUF;
            float* h2w = h2buf + ((t & 1) ^ 1) * HBUF;
            float a0 = bias0, a1 = bias1, a2 = bias2, a3 = bias3;
            f4 b1A, b1B, b2A, b2B;
            cload4(&b1A, h1r + tid * 4);        cload4(&b2A, h2r + tid * 4);
            cload4(&b1B, h1r + CHW + tid * 4);  cload4(&b2B, h2r + CHW + tid * 4);
            WAITVM(2);                          // chunk 0 pair arrived
            st1[0][tid] = b1A;  st2[0][tid] = b2A;
            cload4(&b1A, h1r + 2 * CHW + tid * 4);
            cload4(&b2A, h2r + 2 * CHW + tid * 4);
            BARR;
            #pragma unroll 1
            for (int cc = 0; cc < NCH; cc += 2) {
                if (cc + 2 < NCH) { WAITVM(2); } else { WAITVM(0); }
                st1[1][tid] = b1B;  st2[1][tid] = b2B;
                if (cc + 3 < NCH) {
                    cload4(&b1B, h1r + (size_t)(cc + 3) * CHW + tid * 4);
                    cload4(&b2B, h2r + (size_t)(cc + 3) * CHW + tid * 4);
                }
                CONSUME1(0, cc * KG);
                BARR;
                if (cc + 2 < NCH) {
                    if (cc + 3 < NCH) { WAITVM(2); } else { WAITVM(0); }
                    st1[0][tid] = b1A;  st2[0][tid] = b2A;
                    if (cc + 4 < NCH) {
                        cload4(&b1A, h1r + (size_t)(cc + 4) * CHW + tid * 4);
                        cload4(&b2A, h2r + (size_t)(cc + 4) * CHW + tid * 4);
                    }
                }
                CONSUME1(1, (cc + 1) * KG);
                BARR;
            }
            float ig = sigf(a0), fg = sigf(a1), gg = tanhf(a2), og = sigf(a3);
            c = fg * c + ig * gg;
            float h = og * tanhf(c);
            cstore(h2w + (js >> 2) * 256 + b * 4 + (js & 3), h);   // recurrent state
            out[((size_t)t * BATCH + b) * HID + js] = h;           // final output
        }
    }
}

// ============ epilogue: y_pred = h2[T-1] @ Wlin^T + b ============
// h2[T-1] fp32 is in out[t=SEQ-1] (plain stores, visible at kernel boundary).
__global__ void lstm_finalize(const float* __restrict__ Wlin, const float* __restrict__ blin,
                              float* __restrict__ out)
{
    __shared__ float red[256];
    const int b = blockIdx.x, tid = threadIdx.x;
    const float* h2 = out + ((size_t)(SEQ - 1) * BATCH + b) * HID;
    float p = 0.0f;
    for (int k = tid; k < HID; k += 256) p += h2[k] * Wlin[k];
    red[tid] = p;
    __syncthreads();
    for (int s = 128; s > 0; s >>= 1) {
        if (tid < s) red[tid] += red[tid + s];
        __syncthreads();
    }
    if (tid == 0) out[(size_t)SEQ * BATCH * HID + b] = blin[0] + red[0];
}

extern "C" void kernel_launch(void* const* d_in, const int* in_sizes, int n_in,
                              void* d_out, int out_size, void* d_ws, size_t ws_size,
                              hipStream_t stream) {
    const float* x     = (const float*)d_in[0];
    const float* Wih0  = (const float*)d_in[1];
    const float* Whh0  = (const float*)d_in[2];
    const float* bih0  = (const float*)d_in[3];
    const float* bhh0  = (const float*)d_in[4];
    const float* Wih1  = (const float*)d_in[5];
    const float* Whh1  = (const float*)d_in[6];
    const float* bih1  = (const float*)d_in[7];
    const float* bhh1  = (const float*)d_in[8];
    const float* Wlin  = (const float*)d_in[9];
    const float* blin  = (const float*)d_in[10];
    float* out = (float*)d_out;

    float* ws = (float*)d_ws;
    float* h1buf = ws;                       // 2 * 65536 floats  (h1 ping-pong, [kg][b][4])
    float* h2buf = ws + 2 * HBUF;            // 2 * 65536 floats  (h2 ping-pong)
    uint32_t* flags = (uint32_t*)(ws + 4 * HBUF);   // 256 u32 (init barrier)
    uint32_t* grp   = flags + NBLK;                  // 8 u32 (round counters)

    lstm_fused<<<dim3(NBLK), dim3(NTHR), 0, stream>>>(
        x, Wih0, Whh0, bih0, bhh0, Wih1, Whh1, bih1, bhh1, out, h1buf, h2buf, flags, grp);
    lstm_finalize<<<dim3(BATCH), dim3(256), 0, stream>>>(Wlin, blin, out);
}